// Round 1
// baseline (1189.162 us; speedup 1.0000x reference)
//
#include <hip/hip_runtime.h>

// EMA Vector Quantizer, MI355X fp32 VALU version.
// z: (32,64,64,64) fp32, weight: (1024,64) fp32.
// Outputs flat: q (8388608) | loss (1) | commitment_loss (1) | count (1024) | sum (65536)

#define HWsz   4096            // 64*64 spatial
#define Dd     64
#define Kk     1024
#define NBATCH 32
#define NTOT   (NBATCH * HWsz)     // 131072 vectors
#define QSIZE  (NTOT * Dd)         // 8388608
#define BETA_C 0.25f

// ---------------- prologue: codeword squared norms -> ws ----------------
__global__ __launch_bounds__(256) void c2_kernel(const float* __restrict__ w,
                                                 float* __restrict__ c2) {
    int k = blockIdx.x * 256 + threadIdx.x;   // grid = 4 blocks
    const float4* c4 = reinterpret_cast<const float4*>(w + k * Dd);
    float s0 = 0.f, s1 = 0.f, s2 = 0.f, s3 = 0.f;
#pragma unroll
    for (int q = 0; q < 16; ++q) {
        float4 cq = c4[q];
        s0 = fmaf(cq.x, cq.x, s0);
        s1 = fmaf(cq.y, cq.y, s1);
        s2 = fmaf(cq.z, cq.z, s2);
        s3 = fmaf(cq.w, cq.w, s3);
    }
    c2[k] = (s0 + s1) + (s2 + s3);
}

// ---------------- main: per-thread z vector, loop all K codes ----------------
__global__ __launch_bounds__(256) void vq_main(const float* __restrict__ z,
                                               const float* __restrict__ w,
                                               const float* __restrict__ c2,
                                               float* __restrict__ out,
                                               float* __restrict__ accum) {
    const int n  = blockIdx.x * 256 + threadIdx.x;   // grid = 512 blocks
    const int b  = n >> 12;          // / 4096
    const int hw = n & 4095;
    const float* zp = z + (size_t)b * (Dd * HWsz) + hw;

    // load my z vector (coalesced per-d across lanes: stride HWsz)
    float zv[Dd];
#pragma unroll
    for (int i = 0; i < Dd; ++i) zv[i] = zp[(size_t)i * HWsz];

    float best  = 3.4e38f;
    int   bestk = 0;

#pragma unroll 2
    for (int k = 0; k < Kk; ++k) {
        // wave-uniform address -> expect s_load scalarization
        const float4* c4 = reinterpret_cast<const float4*>(w + k * Dd);
        float a0 = 0.f, a1 = 0.f, a2 = 0.f, a3 = 0.f;
#pragma unroll
        for (int q = 0; q < 16; ++q) {
            float4 cq = c4[q];
            a0 = fmaf(zv[4 * q + 0], cq.x, a0);
            a1 = fmaf(zv[4 * q + 1], cq.y, a1);
            a2 = fmaf(zv[4 * q + 2], cq.z, a2);
            a3 = fmaf(zv[4 * q + 3], cq.w, a3);
        }
        float dot   = (a0 + a1) + (a2 + a3);
        float score = fmaf(-2.f, dot, c2[k]);   // ||c||^2 - 2 z.c  (argmin-equivalent)
        if (score < best) { best = score; bestk = k; }   // strict < : first-index tie-break
    }

    // ---- epilogue ----
    // gather winning codeword (per-lane scattered, L1/L2-hot)
    const float4* cb4 = reinterpret_cast<const float4*>(w + bestk * Dd);
    float cb[Dd];
#pragma unroll
    for (int q = 0; q < 16; ++q) {
        float4 cq = cb4[q];
        cb[4 * q + 0] = cq.x; cb[4 * q + 1] = cq.y;
        cb[4 * q + 2] = cq.z; cb[4 * q + 3] = cq.w;
    }

    // q = z + (c - z): bit-match reference straight-through arithmetic
    float* qp = out + (size_t)b * (Dd * HWsz) + hw;
#pragma unroll
    for (int i = 0; i < Dd; ++i) qp[(size_t)i * HWsz] = zv[i] + (cb[i] - zv[i]);

    // count
    atomicAdd(out + QSIZE + 2 + bestk, 1.0f);

    // sum: scatter-add my z vector into row bestk
    float* sp = out + QSIZE + 2 + Kk + (size_t)bestk * Dd;
#pragma unroll
    for (int i = 0; i < Dd; ++i) atomicAdd(sp + i, zv[i]);

    // commitment partial: direct sum of (z - c)^2, matching reference form
    float part = 0.f;
#pragma unroll
    for (int i = 0; i < Dd; ++i) {
        float dlt = zv[i] - cb[i];
        part = fmaf(dlt, dlt, part);
    }
#pragma unroll
    for (int off = 32; off > 0; off >>= 1) part += __shfl_down(part, off, 64);

    __shared__ float red[4];
    const int lane = threadIdx.x & 63, wid = threadIdx.x >> 6;
    if (lane == 0) red[wid] = part;
    __syncthreads();
    if (threadIdx.x == 0)
        atomicAdd(accum, (red[0] + red[1]) + (red[2] + red[3]));
}

// ---------------- finisher: losses ----------------
__global__ void vq_finish(const float* __restrict__ accum, float* __restrict__ out) {
    float c = accum[0] / (float)QSIZE;
    out[QSIZE]     = BETA_C * c;   // loss
    out[QSIZE + 1] = c;            // commitment_loss
}

extern "C" void kernel_launch(void* const* d_in, const int* in_sizes, int n_in,
                              void* d_out, int out_size, void* d_ws, size_t ws_size,
                              hipStream_t stream) {
    const float* z = (const float*)d_in[0];
    const float* w = (const float*)d_in[1];
    float* out = (float*)d_out;

    // ws layout: [0..63] commitment accumulator (use [0]); [64..] c2 (1024 floats)
    float* accum = (float*)d_ws;
    float* c2    = (float*)d_ws + 64;

    // zero the accumulated output regions (harness poisons with 0xAA)
    hipMemsetAsync(out + QSIZE, 0, (size_t)(2 + Kk + Kk * Dd) * sizeof(float), stream);
    hipMemsetAsync(accum, 0, 64 * sizeof(float), stream);

    c2_kernel<<<Kk / 256, 256, 0, stream>>>(w, c2);
    vq_main<<<NTOT / 256, 256, 0, stream>>>(z, w, c2, out, accum);
    vq_finish<<<1, 1, 0, stream>>>(accum, out);
}

// Round 2
// 487.817 us; speedup vs baseline: 2.4377x; 2.4377x over previous
//
#include <hip/hip_runtime.h>

// EMA Vector Quantizer — MFMA bf16x3-split version for MI355X (gfx950).
// z: (32,64,64,64) fp32  -> N=131072 rows of D=64 (d-stride = 4096 floats)
// w: (1024,64) fp32 codebook.
// Out flat: q (8388608) | loss (1) | commitment (1) | count (1024) | sum (65536)

#define HWsz   4096
#define Dd     64
#define Kk     1024
#define NTOT   131072
#define QSIZE  (NTOT * Dd)
#define BETA_C 0.25f

typedef float  f32x4  __attribute__((ext_vector_type(4)));
typedef short  bf16x8 __attribute__((ext_vector_type(8)));

__device__ __forceinline__ unsigned short f2bf(float f) {
    unsigned u = __float_as_uint(f);
    u += 0x7FFF + ((u >> 16) & 1);          // round-to-nearest-even
    return (unsigned short)(u >> 16);
}
__device__ __forceinline__ float bf2f(unsigned short b) {
    return __uint_as_float(((unsigned)b) << 16);
}

// ---------------- prep 1: codeword squared norms (fp32, exact) ----------------
__global__ __launch_bounds__(256) void c2_kernel(const float* __restrict__ w,
                                                 float* __restrict__ c2) {
    int k = blockIdx.x * 256 + threadIdx.x;           // 4 blocks
    const float4* c4 = reinterpret_cast<const float4*>(w + k * Dd);
    float s0 = 0.f, s1 = 0.f, s2 = 0.f, s3 = 0.f;
#pragma unroll
    for (int q = 0; q < 16; ++q) {
        float4 cq = c4[q];
        s0 = fmaf(cq.x, cq.x, s0); s1 = fmaf(cq.y, cq.y, s1);
        s2 = fmaf(cq.z, cq.z, s2); s3 = fmaf(cq.w, cq.w, s3);
    }
    c2[k] = (s0 + s1) + (s2 + s3);
}

// ---------------- prep 2: split codebook into B-fragment layout ----------------
// B-frag for mfma_f32_16x16x32_bf16: lane l holds B[k=(l>>4)*8+j][col=l&15], j=0..7.
// Stored as ushort8 records: rec = (ctile*2 + kstep)*64 + lane.
__global__ __launch_bounds__(256) void wsplit_kernel(const float* __restrict__ w,
                                                     unsigned short* __restrict__ whi,
                                                     unsigned short* __restrict__ wlo) {
    int t = blockIdx.x * 256 + threadIdx.x;           // 256 blocks -> 65536 threads
    int k = t >> 6, d = t & 63;
    float v = w[t];
    unsigned short hb = f2bf(v);
    unsigned short lb = f2bf(v - bf2f(hb));
    int ctile = k >> 4, col = k & 15;
    int s = d >> 5, kg = (d >> 3) & 3, j = d & 7;
    int idx = (((ctile * 2 + s) * 64) + kg * 16 + col) * 8 + j;
    whi[idx] = hb; wlo[idx] = lb;
}

// ---------------- main ----------------
__global__ __launch_bounds__(256) void vq_main(const float* __restrict__ z,
                                               const float* __restrict__ w,
                                               const float* __restrict__ c2,
                                               const unsigned short* __restrict__ whi,
                                               const unsigned short* __restrict__ wlo,
                                               float* __restrict__ out,
                                               float* __restrict__ accum) {
    const int lane = threadIdx.x & 63;
    const int wid  = threadIdx.x >> 6;
    const int rt   = blockIdx.x * 4 + wid;            // row-tile 0..8191 (16 rows each)
    const int b    = rt >> 8;                         // 256 row-tiles per batch image
    const int hw0  = (rt & 255) << 4;
    const int col  = lane & 15;                       // z-row within tile / code col
    const int kg   = lane >> 4;                       // k-group (8 contiguous d each)

    // ---- load my 16 z elements (row=col, d = 32*s + kg*8 + j), keep fp32 ----
    const float* zbase = z + (size_t)b * (Dd * HWsz) + hw0 + col;
    float zv[16];
#pragma unroll
    for (int s = 0; s < 2; ++s)
#pragma unroll
        for (int j = 0; j < 8; ++j)
            zv[s * 8 + j] = zbase[(size_t)(32 * s + kg * 8 + j) * HWsz];

    // ---- build A-fragments: hi/lo bf16 split ----
    bf16x8 zhi[2], zlo[2];
#pragma unroll
    for (int s = 0; s < 2; ++s) {
        bf16x8 h, l;
#pragma unroll
        for (int j = 0; j < 8; ++j) {
            unsigned short hb = f2bf(zv[s * 8 + j]);
            unsigned short lb = f2bf(zv[s * 8 + j] - bf2f(hb));
            h[j] = (short)hb; l[j] = (short)lb;
        }
        zhi[s] = h; zlo[s] = l;
    }

    // ---- scan all 1024 codes in 64 tiles of 16 ----
    float best0 = 3.4e38f, best1 = 3.4e38f, best2 = 3.4e38f, best3 = 3.4e38f;
    int   bk0 = 0, bk1 = 0, bk2 = 0, bk3 = 0;

    const bf16x8* ph = reinterpret_cast<const bf16x8*>(whi);
    const bf16x8* pl = reinterpret_cast<const bf16x8*>(wlo);

#pragma unroll 2
    for (int ct = 0; ct < 64; ++ct) {
        bf16x8 wh0 = ph[(ct * 2 + 0) * 64 + lane];
        bf16x8 wh1 = ph[(ct * 2 + 1) * 64 + lane];
        bf16x8 wl0 = pl[(ct * 2 + 0) * 64 + lane];
        bf16x8 wl1 = pl[(ct * 2 + 1) * 64 + lane];

        f32x4 za = {0.f, 0.f, 0.f, 0.f};              // hi*hi + hi*lo chain
        f32x4 zb = {0.f, 0.f, 0.f, 0.f};              // lo*hi chain (independent)
        za = __builtin_amdgcn_mfma_f32_16x16x32_bf16(zhi[0], wh0, za, 0, 0, 0);
        za = __builtin_amdgcn_mfma_f32_16x16x32_bf16(zhi[1], wh1, za, 0, 0, 0);
        za = __builtin_amdgcn_mfma_f32_16x16x32_bf16(zhi[0], wl0, za, 0, 0, 0);
        za = __builtin_amdgcn_mfma_f32_16x16x32_bf16(zhi[1], wl1, za, 0, 0, 0);
        zb = __builtin_amdgcn_mfma_f32_16x16x32_bf16(zlo[0], wh0, zb, 0, 0, 0);
        zb = __builtin_amdgcn_mfma_f32_16x16x32_bf16(zlo[1], wh1, zb, 0, 0, 0);

        float cv = c2[ct * 16 + col];                 // L1-hot 4 KB table
        int   kc = ct * 16 + col;
        // C layout: lane holds rows (lane>>4)*4 + r, col = lane&15  [m89/m91]
        {
            float s = fmaf(-2.f, za[0] + zb[0], cv);
            if (s < best0) { best0 = s; bk0 = kc; }
        }
        {
            float s = fmaf(-2.f, za[1] + zb[1], cv);
            if (s < best1) { best1 = s; bk1 = kc; }
        }
        {
            float s = fmaf(-2.f, za[2] + zb[2], cv);
            if (s < best2) { best2 = s; bk2 = kc; }
        }
        {
            float s = fmaf(-2.f, za[3] + zb[3], cv);
            if (s < best3) { best3 = s; bk3 = kc; }
        }
    }

    // ---- merge argmin across the 16 lanes sharing each row group ----
    // lanes l, l^1, l^2, l^4, l^8 span the 16 code-column owners of rows (l>>4)*4+r
    float best[4] = {best0, best1, best2, best3};
    int   bk[4]   = {bk0, bk1, bk2, bk3};
#pragma unroll
    for (int off = 1; off < 16; off <<= 1) {
#pragma unroll
        for (int r = 0; r < 4; ++r) {
            float ob = __shfl_xor(best[r], off, 64);
            int   ok = __shfl_xor(bk[r],   off, 64);
            if (ob < best[r] || (ob == best[r] && ok < bk[r])) {  // first-index tie-break
                best[r] = ob; bk[r] = ok;
            }
        }
    }

    // ---- fetch bestk of MY row (row = col): held by lane (col>>2)*16, reg col&3 ----
    int srcl = (col >> 2) << 4;
    int c0 = __shfl(bk[0], srcl, 64);
    int c1 = __shfl(bk[1], srcl, 64);
    int c2r = __shfl(bk[2], srcl, 64);
    int c3 = __shfl(bk[3], srcl, 64);
    int rsel = col & 3;
    int mybk = (rsel == 0) ? c0 : (rsel == 1) ? c1 : (rsel == 2) ? c2r : c3;

    // ---- count (one lane per row) ----
    if (lane < 16) atomicAdd(out + QSIZE + 2 + mybk, 1.0f);

    // ---- gather winning codeword fp32 for my 16 d's ----
    float cb[16];
#pragma unroll
    for (int s = 0; s < 2; ++s) {
        const float4* cw = reinterpret_cast<const float4*>(w + mybk * Dd + 32 * s + kg * 8);
        float4 p0 = cw[0], p1 = cw[1];
        cb[s * 8 + 0] = p0.x; cb[s * 8 + 1] = p0.y; cb[s * 8 + 2] = p0.z; cb[s * 8 + 3] = p0.w;
        cb[s * 8 + 4] = p1.x; cb[s * 8 + 5] = p1.y; cb[s * 8 + 6] = p1.z; cb[s * 8 + 7] = p1.w;
    }

    // ---- q write (reference straight-through arithmetic), sum scatter, commitment ----
    float* qbase = out + (size_t)b * (Dd * HWsz) + hw0 + col;
    float* sumb  = out + QSIZE + 2 + Kk + (size_t)mybk * Dd;
    float commit = 0.f;
#pragma unroll
    for (int s = 0; s < 2; ++s)
#pragma unroll
        for (int j = 0; j < 8; ++j) {
            int   d  = 32 * s + kg * 8 + j;
            float zz = zv[s * 8 + j];
            float cc = cb[s * 8 + j];
            qbase[(size_t)d * HWsz] = zz + (cc - zz);
            atomicAdd(sumb + d, zz);
            float dd = zz - cc;
            commit = fmaf(dd, dd, commit);
        }

#pragma unroll
    for (int off = 32; off > 0; off >>= 1) commit += __shfl_down(commit, off, 64);

    __shared__ float red[4];
    if (lane == 0) red[wid] = commit;
    __syncthreads();
    if (threadIdx.x == 0)
        atomicAdd(accum, (red[0] + red[1]) + (red[2] + red[3]));
}

// ---------------- finisher ----------------
__global__ void vq_finish(const float* __restrict__ accum, float* __restrict__ out) {
    float c = accum[0] / (float)QSIZE;
    out[QSIZE]     = BETA_C * c;
    out[QSIZE + 1] = c;
}

extern "C" void kernel_launch(void* const* d_in, const int* in_sizes, int n_in,
                              void* d_out, int out_size, void* d_ws, size_t ws_size,
                              hipStream_t stream) {
    const float* z = (const float*)d_in[0];
    const float* w = (const float*)d_in[1];
    float* out = (float*)d_out;

    // ws layout (floats): [0..63] accum | [64..1087] c2 | then whi (64K bf16) | wlo (64K bf16)
    float* accum = (float*)d_ws;
    float* c2    = (float*)d_ws + 64;
    unsigned short* whi = (unsigned short*)((float*)d_ws + 64 + Kk);
    unsigned short* wlo = whi + (Kk * Dd);

    hipMemsetAsync(out + QSIZE, 0, (size_t)(2 + Kk + Kk * Dd) * sizeof(float), stream);
    hipMemsetAsync(accum, 0, 64 * sizeof(float), stream);

    c2_kernel<<<Kk / 256, 256, 0, stream>>>(w, c2);
    wsplit_kernel<<<(Kk * Dd) / 256, 256, 0, stream>>>(w, whi, wlo);
    vq_main<<<NTOT / 64, 256, 0, stream>>>(z, w, c2, whi, wlo, out, accum);
    vq_finish<<<1, 1, 0, stream>>>(accum, out);
}

// Round 3
// 262.484 us; speedup vs baseline: 4.5304x; 1.8585x over previous
//
#include <hip/hip_runtime.h>

// EMA Vector Quantizer — R3: phase-split, atomic-free stats path.
// z: (32,64,64,64) fp32; w: (1024,64) fp32.
// Out flat: q (8388608) | loss (1) | commitment (1) | count (1024) | sum (65536)

#define HWsz   4096
#define Dd     64
#define Kk     1024
#define NB     32
#define NTOT   131072
#define QSIZE  (NTOT * Dd)
#define BETA_C 0.25f

typedef float  f32x4  __attribute__((ext_vector_type(4)));
typedef short  bf16x8 __attribute__((ext_vector_type(8)));

__device__ __forceinline__ unsigned short f2bf(float f) {
    unsigned u = __float_as_uint(f);
    u += 0x7FFF + ((u >> 16) & 1);
    return (unsigned short)(u >> 16);
}
__device__ __forceinline__ float bf2f(unsigned short b) {
    return __uint_as_float(((unsigned)b) << 16);
}

// ---------------- prep 1: codeword squared norms ----------------
__global__ __launch_bounds__(256) void c2_kernel(const float* __restrict__ w,
                                                 float* __restrict__ c2) {
    int k = blockIdx.x * 256 + threadIdx.x;
    const float4* c4 = reinterpret_cast<const float4*>(w + k * Dd);
    float s0 = 0.f, s1 = 0.f, s2 = 0.f, s3 = 0.f;
#pragma unroll
    for (int q = 0; q < 16; ++q) {
        float4 cq = c4[q];
        s0 = fmaf(cq.x, cq.x, s0); s1 = fmaf(cq.y, cq.y, s1);
        s2 = fmaf(cq.z, cq.z, s2); s3 = fmaf(cq.w, cq.w, s3);
    }
    c2[k] = (s0 + s1) + (s2 + s3);
}

// ---------------- prep 2: split codebook into B-fragment layout ----------------
__global__ __launch_bounds__(256) void wsplit_kernel(const float* __restrict__ w,
                                                     unsigned short* __restrict__ whi,
                                                     unsigned short* __restrict__ wlo) {
    int t = blockIdx.x * 256 + threadIdx.x;
    int k = t >> 6, d = t & 63;
    float v = w[t];
    unsigned short hb = f2bf(v);
    unsigned short lb = f2bf(v - bf2f(hb));
    int ctile = k >> 4, col = k & 15;
    int s = d >> 5, kg = (d >> 3) & 3, j = d & 7;
    int idx = (((ctile * 2 + s) * 64) + kg * 16 + col) * 8 + j;
    whi[idx] = hb; wlo[idx] = lb;
}

// ---------------- phase 1: distances, argmin, q, commitment, idx ----------------
__global__ __launch_bounds__(256) void vq_dist(const float* __restrict__ z,
                                               const float* __restrict__ w,
                                               const float* __restrict__ c2,
                                               const unsigned short* __restrict__ whi,
                                               const unsigned short* __restrict__ wlo,
                                               float* __restrict__ out,
                                               float* __restrict__ accum,
                                               int* __restrict__ idx_ws) {
    const int lane = threadIdx.x & 63;
    const int wid  = threadIdx.x >> 6;
    const int rt   = blockIdx.x * 4 + wid;
    const int b    = rt >> 8;
    const int hw0  = (rt & 255) << 4;
    const int col  = lane & 15;
    const int kg   = lane >> 4;

    const float* zbase = z + (size_t)b * (Dd * HWsz) + hw0 + col;
    float zv[16];
#pragma unroll
    for (int s = 0; s < 2; ++s)
#pragma unroll
        for (int j = 0; j < 8; ++j)
            zv[s * 8 + j] = zbase[(size_t)(32 * s + kg * 8 + j) * HWsz];

    bf16x8 zhi[2], zlo[2];
#pragma unroll
    for (int s = 0; s < 2; ++s) {
        bf16x8 h, l;
#pragma unroll
        for (int j = 0; j < 8; ++j) {
            unsigned short hb = f2bf(zv[s * 8 + j]);
            unsigned short lb = f2bf(zv[s * 8 + j] - bf2f(hb));
            h[j] = (short)hb; l[j] = (short)lb;
        }
        zhi[s] = h; zlo[s] = l;
    }

    float best0 = 3.4e38f, best1 = 3.4e38f, best2 = 3.4e38f, best3 = 3.4e38f;
    int   bk0 = 0, bk1 = 0, bk2 = 0, bk3 = 0;

    const bf16x8* ph = reinterpret_cast<const bf16x8*>(whi);
    const bf16x8* pl = reinterpret_cast<const bf16x8*>(wlo);

#pragma unroll 2
    for (int ct = 0; ct < 64; ++ct) {
        bf16x8 wh0 = ph[(ct * 2 + 0) * 64 + lane];
        bf16x8 wh1 = ph[(ct * 2 + 1) * 64 + lane];
        bf16x8 wl0 = pl[(ct * 2 + 0) * 64 + lane];
        bf16x8 wl1 = pl[(ct * 2 + 1) * 64 + lane];

        f32x4 za = {0.f, 0.f, 0.f, 0.f};
        f32x4 zb = {0.f, 0.f, 0.f, 0.f};
        za = __builtin_amdgcn_mfma_f32_16x16x32_bf16(zhi[0], wh0, za, 0, 0, 0);
        za = __builtin_amdgcn_mfma_f32_16x16x32_bf16(zhi[1], wh1, za, 0, 0, 0);
        za = __builtin_amdgcn_mfma_f32_16x16x32_bf16(zhi[0], wl0, za, 0, 0, 0);
        za = __builtin_amdgcn_mfma_f32_16x16x32_bf16(zhi[1], wl1, za, 0, 0, 0);
        zb = __builtin_amdgcn_mfma_f32_16x16x32_bf16(zlo[0], wh0, zb, 0, 0, 0);
        zb = __builtin_amdgcn_mfma_f32_16x16x32_bf16(zlo[1], wh1, zb, 0, 0, 0);

        float cv = c2[ct * 16 + col];
        int   kc = ct * 16 + col;
        { float s = fmaf(-2.f, za[0] + zb[0], cv); if (s < best0) { best0 = s; bk0 = kc; } }
        { float s = fmaf(-2.f, za[1] + zb[1], cv); if (s < best1) { best1 = s; bk1 = kc; } }
        { float s = fmaf(-2.f, za[2] + zb[2], cv); if (s < best2) { best2 = s; bk2 = kc; } }
        { float s = fmaf(-2.f, za[3] + zb[3], cv); if (s < best3) { best3 = s; bk3 = kc; } }
    }

    float best[4] = {best0, best1, best2, best3};
    int   bk[4]   = {bk0, bk1, bk2, bk3};
#pragma unroll
    for (int off = 1; off < 16; off <<= 1) {
#pragma unroll
        for (int r = 0; r < 4; ++r) {
            float ob = __shfl_xor(best[r], off, 64);
            int   ok = __shfl_xor(bk[r],   off, 64);
            if (ob < best[r] || (ob == best[r] && ok < bk[r])) { best[r] = ob; bk[r] = ok; }
        }
    }

    int srcl = (col >> 2) << 4;
    int c0 = __shfl(bk[0], srcl, 64);
    int c1 = __shfl(bk[1], srcl, 64);
    int c2r = __shfl(bk[2], srcl, 64);
    int c3 = __shfl(bk[3], srcl, 64);
    int rsel = col & 3;
    int mybk = (rsel == 0) ? c0 : (rsel == 1) ? c1 : (rsel == 2) ? c2r : c3;

    // idx write (one lane per row; lanes 0..15 have kg==0, row == lane)
    if (lane < 16) idx_ws[(size_t)b * HWsz + hw0 + col] = mybk;

    // gather winning codeword
    float cb[16];
#pragma unroll
    for (int s = 0; s < 2; ++s) {
        const float4* cw = reinterpret_cast<const float4*>(w + mybk * Dd + 32 * s + kg * 8);
        float4 p0 = cw[0], p1 = cw[1];
        cb[s * 8 + 0] = p0.x; cb[s * 8 + 1] = p0.y; cb[s * 8 + 2] = p0.z; cb[s * 8 + 3] = p0.w;
        cb[s * 8 + 4] = p1.x; cb[s * 8 + 5] = p1.y; cb[s * 8 + 6] = p1.z; cb[s * 8 + 7] = p1.w;
    }

    // q write (reference straight-through arithmetic) + commitment partial
    float* qbase = out + (size_t)b * (Dd * HWsz) + hw0 + col;
    float commit = 0.f;
#pragma unroll
    for (int s = 0; s < 2; ++s)
#pragma unroll
        for (int j = 0; j < 8; ++j) {
            int   d  = 32 * s + kg * 8 + j;
            float zz = zv[s * 8 + j];
            float cc = cb[s * 8 + j];
            qbase[(size_t)d * HWsz] = zz + (cc - zz);
            float dd = zz - cc;
            commit = fmaf(dd, dd, commit);
        }

#pragma unroll
    for (int off = 32; off > 0; off >>= 1) commit += __shfl_down(commit, off, 64);

    __shared__ float red[4];
    if (lane == 0) red[wid] = commit;
    __syncthreads();
    if (threadIdx.x == 0)
        atomicAdd(accum, (red[0] + red[1]) + (red[2] + red[3]));
}

// ---------------- phase 2: per-(b,d) LDS segment accumulation ----------------
__global__ __launch_bounds__(256) void vq_stats(const float* __restrict__ z,
                                                const int* __restrict__ idx_ws,
                                                float* __restrict__ psum,
                                                float* __restrict__ pcnt) {
    const int bd = blockIdx.x;          // b*64 + d, grid = 2048
    const int b = bd >> 6, d = bd & 63;
    const bool docnt = (d == 0);

    __shared__ float acc[Kk];
    __shared__ float cnt[Kk];
    for (int i = threadIdx.x; i < Kk; i += 256) { acc[i] = 0.f; cnt[i] = 0.f; }
    __syncthreads();

    const int4*   ip = reinterpret_cast<const int4*>(idx_ws + (size_t)b * HWsz);
    const float4* zp = reinterpret_cast<const float4*>(z + ((size_t)b * Dd + d) * HWsz);
#pragma unroll
    for (int c = threadIdx.x; c < HWsz / 4; c += 256) {
        int4   k4 = ip[c];
        float4 v4 = zp[c];
        atomicAdd(&acc[k4.x], v4.x);
        atomicAdd(&acc[k4.y], v4.y);
        atomicAdd(&acc[k4.z], v4.z);
        atomicAdd(&acc[k4.w], v4.w);
        if (docnt) {
            atomicAdd(&cnt[k4.x], 1.f);
            atomicAdd(&cnt[k4.y], 1.f);
            atomicAdd(&cnt[k4.z], 1.f);
            atomicAdd(&cnt[k4.w], 1.f);
        }
    }
    __syncthreads();

    float* po = psum + (size_t)bd * Kk;
    for (int i = threadIdx.x; i < Kk; i += 256) po[i] = acc[i];
    if (docnt) {
        float* pc = pcnt + (size_t)b * Kk;
        for (int i = threadIdx.x; i < Kk; i += 256) pc[i] = cnt[i];
    }
}

// ---------------- phase 3: reduce partials over batch ----------------
__global__ __launch_bounds__(256) void vq_reduce(const float* __restrict__ psum,
                                                 const float* __restrict__ pcnt,
                                                 float* __restrict__ out) {
    int t = blockIdx.x * 256 + threadIdx.x;   // 65536 threads
    int k = t & 1023, d = t >> 10;
    float s = 0.f;
#pragma unroll
    for (int b = 0; b < NB; ++b)
        s += psum[(((size_t)b * Dd + d) << 10) + k];
    out[QSIZE + 2 + Kk + (size_t)k * Dd + d] = s;
    if (t < Kk) {
        float c = 0.f;
#pragma unroll
        for (int b = 0; b < NB; ++b) c += pcnt[((size_t)b << 10) + t];
        out[QSIZE + 2 + t] = c;
    }
}

// ---------------- finisher ----------------
__global__ void vq_finish(const float* __restrict__ accum, float* __restrict__ out) {
    float c = accum[0] / (float)QSIZE;
    out[QSIZE]     = BETA_C * c;
    out[QSIZE + 1] = c;
}

extern "C" void kernel_launch(void* const* d_in, const int* in_sizes, int n_in,
                              void* d_out, int out_size, void* d_ws, size_t ws_size,
                              hipStream_t stream) {
    const float* z = (const float*)d_in[0];
    const float* w = (const float*)d_in[1];
    float* out = (float*)d_out;

    // ws layout (floats):
    // [0..63] accum | [64..1087] c2 | whi 65536 us | wlo 65536 us |
    // idx 131072 int | psum 2048*1024 f | pcnt 32*1024 f
    float* accum = (float*)d_ws;
    float* c2    = (float*)d_ws + 64;
    unsigned short* whi = (unsigned short*)((float*)d_ws + 64 + Kk);
    unsigned short* wlo = whi + (Kk * Dd);
    int*   idx_ws = (int*)(wlo + (Kk * Dd));
    float* psum   = (float*)(idx_ws + NTOT);
    float* pcnt   = psum + (size_t)NB * Dd * Kk;

    hipMemsetAsync(accum, 0, 64 * sizeof(float), stream);

    c2_kernel<<<Kk / 256, 256, 0, stream>>>(w, c2);
    wsplit_kernel<<<(Kk * Dd) / 256, 256, 0, stream>>>(w, whi, wlo);
    vq_dist<<<NTOT / 64, 256, 0, stream>>>(z, w, c2, whi, wlo, out, accum, idx_ws);
    vq_stats<<<NB * Dd, 256, 0, stream>>>(z, idx_ws, psum, pcnt);
    vq_reduce<<<(Kk * Dd) / 256, 256, 0, stream>>>(psum, pcnt, out);
    vq_finish<<<1, 1, 0, stream>>>(accum, out);
}

// Round 4
// 242.958 us; speedup vs baseline: 4.8945x; 1.0804x over previous
//
#include <hip/hip_runtime.h>

// EMA Vector Quantizer — R4: 64 rows/wave MFMA blocking + chunked LDS stats.
// z: (32,64,64,64) fp32; w: (1024,64) fp32.
// Out flat: q (8388608) | loss (1) | commitment (1) | count (1024) | sum (65536)

#define HWsz   4096
#define Dd     64
#define Kk     1024
#define NB     32
#define NTOT   131072
#define QSIZE  (NTOT * Dd)
#define BETA_C 0.25f

typedef float  f32x4  __attribute__((ext_vector_type(4)));
typedef short  bf16x8 __attribute__((ext_vector_type(8)));

__device__ __forceinline__ unsigned short f2bf(float f) {
    unsigned u = __float_as_uint(f);
    u += 0x7FFF + ((u >> 16) & 1);
    return (unsigned short)(u >> 16);
}
__device__ __forceinline__ float bf2f(unsigned short b) {
    return __uint_as_float(((unsigned)b) << 16);
}

// ---------------- prep: c2 norms + codebook bf16 hi/lo split in B-frag layout ----
__global__ __launch_bounds__(256) void vq_prep(const float* __restrict__ w,
                                               float* __restrict__ c2,
                                               unsigned short* __restrict__ whi,
                                               unsigned short* __restrict__ wlo) {
    int t = blockIdx.x * 256 + threadIdx.x;           // 65536 threads
    int k = t >> 6, d = t & 63;
    float v = w[t];
    unsigned short hb = f2bf(v);
    unsigned short lb = f2bf(v - bf2f(hb));
    int ctile = k >> 4, col = k & 15;
    int s = d >> 5, kg = (d >> 3) & 3, j = d & 7;
    int idx = (((ctile * 2 + s) * 64) + kg * 16 + col) * 8 + j;
    whi[idx] = hb; wlo[idx] = lb;

    if (t < Kk) {                                      // c2 for code t
        const float4* c4 = reinterpret_cast<const float4*>(w + t * Dd);
        float s0 = 0.f, s1 = 0.f, s2 = 0.f, s3 = 0.f;
#pragma unroll
        for (int q = 0; q < 16; ++q) {
            float4 cq = c4[q];
            s0 = fmaf(cq.x, cq.x, s0); s1 = fmaf(cq.y, cq.y, s1);
            s2 = fmaf(cq.z, cq.z, s2); s3 = fmaf(cq.w, cq.w, s3);
        }
        c2[t] = (s0 + s1) + (s2 + s3);
    }
}

// ---------------- phase 1: distances, argmin, q, commitment, idx ----------------
// 512 blocks x 4 waves; each wave owns 64 rows (4 row-tiles of 16).
__global__ __launch_bounds__(256) void vq_dist(const float* __restrict__ z,
                                               const float* __restrict__ w,
                                               const float* __restrict__ c2,
                                               const unsigned short* __restrict__ whi,
                                               const unsigned short* __restrict__ wlo,
                                               float* __restrict__ out,
                                               float* __restrict__ accum,
                                               int* __restrict__ idx_ws) {
    const int lane = threadIdx.x & 63;
    const int wid  = threadIdx.x >> 6;
    const int b    = blockIdx.x >> 4;                  // 16 blocks per image
    const int t0   = (blockIdx.x & 15) * 16 + wid * 4; // first row-tile of this wave
    const int col  = lane & 15;
    const int kg   = lane >> 4;

    // ---- load 4 row-tiles' z, build bf16 hi/lo A-fragments ----
    bf16x8 zhi[4][2], zlo[4][2];
#pragma unroll
    for (int m = 0; m < 4; ++m) {
        const int hw0 = (t0 + m) << 4;
        const float* zbase = z + (size_t)b * (Dd * HWsz) + hw0 + col;
#pragma unroll
        for (int s = 0; s < 2; ++s) {
            bf16x8 h, l;
#pragma unroll
            for (int j = 0; j < 8; ++j) {
                float zz = zbase[(size_t)(32 * s + kg * 8 + j) * HWsz];
                unsigned short hb = f2bf(zz);
                unsigned short lb = f2bf(zz - bf2f(hb));
                h[j] = (short)hb; l[j] = (short)lb;
            }
            zhi[m][s] = h; zlo[m][s] = l;
        }
    }

    float best[4][4];
    int   bk[4][4];
#pragma unroll
    for (int m = 0; m < 4; ++m)
#pragma unroll
        for (int r = 0; r < 4; ++r) { best[m][r] = 3.4e38f; bk[m][r] = 0; }

    const bf16x8* ph = reinterpret_cast<const bf16x8*>(whi);
    const bf16x8* pl = reinterpret_cast<const bf16x8*>(wlo);

    for (int ct = 0; ct < 64; ++ct) {
        bf16x8 wh0 = ph[(ct * 2 + 0) * 64 + lane];
        bf16x8 wh1 = ph[(ct * 2 + 1) * 64 + lane];
        bf16x8 wl0 = pl[(ct * 2 + 0) * 64 + lane];
        bf16x8 wl1 = pl[(ct * 2 + 1) * 64 + lane];

        float cv = c2[ct * 16 + col];
        int   kc = ct * 16 + col;

#pragma unroll
        for (int m = 0; m < 4; ++m) {
            f32x4 za = {0.f, 0.f, 0.f, 0.f};
            f32x4 zb = {0.f, 0.f, 0.f, 0.f};
            za = __builtin_amdgcn_mfma_f32_16x16x32_bf16(zhi[m][0], wh0, za, 0, 0, 0);
            za = __builtin_amdgcn_mfma_f32_16x16x32_bf16(zhi[m][1], wh1, za, 0, 0, 0);
            za = __builtin_amdgcn_mfma_f32_16x16x32_bf16(zhi[m][0], wl0, za, 0, 0, 0);
            za = __builtin_amdgcn_mfma_f32_16x16x32_bf16(zhi[m][1], wl1, za, 0, 0, 0);
            zb = __builtin_amdgcn_mfma_f32_16x16x32_bf16(zlo[m][0], wh0, zb, 0, 0, 0);
            zb = __builtin_amdgcn_mfma_f32_16x16x32_bf16(zlo[m][1], wh1, zb, 0, 0, 0);
#pragma unroll
            for (int r = 0; r < 4; ++r) {
                float s = fmaf(-2.f, za[r] + zb[r], cv);
                if (s < best[m][r]) { best[m][r] = s; bk[m][r] = kc; }
            }
        }
    }

    // ---- merge argmin across the 16 code-column lanes ----
#pragma unroll
    for (int off = 1; off < 16; off <<= 1) {
#pragma unroll
        for (int m = 0; m < 4; ++m)
#pragma unroll
            for (int r = 0; r < 4; ++r) {
                float ob = __shfl_xor(best[m][r], off, 64);
                int   ok = __shfl_xor(bk[m][r],   off, 64);
                if (ob < best[m][r] || (ob == best[m][r] && ok < bk[m][r])) {
                    best[m][r] = ob; bk[m][r] = ok;
                }
            }
    }

    // ---- epilogue per row-tile ----
    float commit = 0.f;
    const int srcl = (col >> 2) << 4;
    const int rsel = col & 3;
#pragma unroll
    for (int m = 0; m < 4; ++m) {
        int c0 = __shfl(bk[m][0], srcl, 64);
        int c1 = __shfl(bk[m][1], srcl, 64);
        int c2r = __shfl(bk[m][2], srcl, 64);
        int c3 = __shfl(bk[m][3], srcl, 64);
        int mybk = (rsel == 0) ? c0 : (rsel == 1) ? c1 : (rsel == 2) ? c2r : c3;

        const int hw0 = (t0 + m) << 4;
        if (lane < 16) idx_ws[(size_t)b * HWsz + hw0 + col] = mybk;

        float* qbase = out + (size_t)b * (Dd * HWsz) + hw0 + col;
#pragma unroll
        for (int s = 0; s < 2; ++s) {
            const float4* cw = reinterpret_cast<const float4*>(w + mybk * Dd + 32 * s + kg * 8);
            float4 p0 = cw[0], p1 = cw[1];
            float cb[8] = {p0.x, p0.y, p0.z, p0.w, p1.x, p1.y, p1.z, p1.w};
#pragma unroll
            for (int j = 0; j < 8; ++j) {
                int   d  = 32 * s + kg * 8 + j;
                float zz = bf2f((unsigned short)zhi[m][s][j]) +
                           bf2f((unsigned short)zlo[m][s][j]);
                float cc = cb[j];
                qbase[(size_t)d * HWsz] = zz + (cc - zz);
                float dd = zz - cc;
                commit = fmaf(dd, dd, commit);
            }
        }
    }

#pragma unroll
    for (int off = 32; off > 0; off >>= 1) commit += __shfl_down(commit, off, 64);

    __shared__ float red[4];
    if (lane == 0) red[wid] = commit;
    __syncthreads();
    if (threadIdx.x == 0)
        atomicAdd(accum, (red[0] + red[1]) + (red[2] + red[3]));
}

// ---------------- phase 2: per-(b, d-chunk) LDS accumulation ----------------
// grid = 32 * 8 = 256 blocks; each handles 8 d-planes of one image.
__global__ __launch_bounds__(256) void vq_stats(const float* __restrict__ z,
                                                const int* __restrict__ idx_ws,
                                                float* __restrict__ psum,
                                                float* __restrict__ pcnt) {
    const int b     = blockIdx.x >> 3;
    const int chunk = blockIdx.x & 7;
    const int dbase = chunk * 8;
    const bool docnt = (chunk == 0);

    __shared__ float acc[8][Kk];
    __shared__ float cnt[Kk];
    for (int i = threadIdx.x; i < 8 * Kk; i += 256)
        acc[i >> 10][i & 1023] = 0.f;
    for (int i = threadIdx.x; i < Kk; i += 256) cnt[i] = 0.f;
    __syncthreads();

    const int4* ip = reinterpret_cast<const int4*>(idx_ws + (size_t)b * HWsz);
#pragma unroll
    for (int it = 0; it < 4; ++it) {
        int c4 = it * 256 + threadIdx.x;              // float4 index within plane
        int4 k4 = ip[c4];
#pragma unroll
        for (int d8 = 0; d8 < 8; ++d8) {
            const float4 v4 = reinterpret_cast<const float4*>(
                z + ((size_t)b * Dd + dbase + d8) * HWsz)[c4];
            atomicAdd(&acc[d8][k4.x], v4.x);
            atomicAdd(&acc[d8][k4.y], v4.y);
            atomicAdd(&acc[d8][k4.z], v4.z);
            atomicAdd(&acc[d8][k4.w], v4.w);
        }
        if (docnt) {
            atomicAdd(&cnt[k4.x], 1.f);
            atomicAdd(&cnt[k4.y], 1.f);
            atomicAdd(&cnt[k4.z], 1.f);
            atomicAdd(&cnt[k4.w], 1.f);
        }
    }
    __syncthreads();

    // psum layout: [b][d][k] contiguous  (b*65536 + d*1024 + k)
    float* po = psum + (size_t)b * (Dd * Kk) + (size_t)dbase * Kk;
    for (int i = threadIdx.x; i < 8 * Kk; i += 256)
        po[i] = acc[i >> 10][i & 1023];
    if (docnt) {
        float* pc = pcnt + (size_t)b * Kk;
        for (int i = threadIdx.x; i < Kk; i += 256) pc[i] = cnt[i];
    }
}

// ---------------- phase 3: reduce over batch + losses ----------------
__global__ __launch_bounds__(256) void vq_reduce(const float* __restrict__ psum,
                                                 const float* __restrict__ pcnt,
                                                 const float* __restrict__ accum,
                                                 float* __restrict__ out) {
    int t = blockIdx.x * 256 + threadIdx.x;   // 65536 threads
    int k = t & 1023, d = t >> 10;
    float s = 0.f;
#pragma unroll
    for (int b = 0; b < NB; ++b)
        s += psum[(size_t)b * (Dd * Kk) + (size_t)d * Kk + k];
    out[QSIZE + 2 + Kk + (size_t)k * Dd + d] = s;
    if (t < Kk) {
        float c = 0.f;
#pragma unroll
        for (int b = 0; b < NB; ++b) c += pcnt[((size_t)b << 10) + t];
        out[QSIZE + 2 + t] = c;
    }
    if (t == 0) {
        float c = accum[0] / (float)QSIZE;
        out[QSIZE]     = BETA_C * c;
        out[QSIZE + 1] = c;
    }
}

extern "C" void kernel_launch(void* const* d_in, const int* in_sizes, int n_in,
                              void* d_out, int out_size, void* d_ws, size_t ws_size,
                              hipStream_t stream) {
    const float* z = (const float*)d_in[0];
    const float* w = (const float*)d_in[1];
    float* out = (float*)d_out;

    // ws layout (floats): [0..63] accum | [64..1087] c2 | whi 65536 us | wlo 65536 us |
    //                     idx 131072 int | psum 32*64*1024 f | pcnt 32*1024 f
    float* accum = (float*)d_ws;
    float* c2    = (float*)d_ws + 64;
    unsigned short* whi = (unsigned short*)((float*)d_ws + 64 + Kk);
    unsigned short* wlo = whi + (Kk * Dd);
    int*   idx_ws = (int*)(wlo + (Kk * Dd));
    float* psum   = (float*)(idx_ws + NTOT);
    float* pcnt   = psum + (size_t)NB * Dd * Kk;

    hipMemsetAsync(accum, 0, 64 * sizeof(float), stream);

    vq_prep<<<(Kk * Dd) / 256, 256, 0, stream>>>(w, c2, whi, wlo);
    vq_dist<<<NTOT / 256, 256, 0, stream>>>(z, w, c2, whi, wlo, out, accum, idx_ws);
    vq_stats<<<NB * 8, 256, 0, stream>>>(z, idx_ws, psum, pcnt);
    vq_reduce<<<(Kk * Dd) / 256, 256, 0, stream>>>(psum, pcnt, accum, out);
}